// Round 3
// baseline (137.745 us; speedup 1.0000x reference)
//
#include <hip/hip_runtime.h>
#include <hip/hip_bf16.h>

// Problem constants
#define NB 4
#define SEQ 2048
#define DM 1024
#define DH 64

typedef __attribute__((ext_vector_type(8))) short bf16x8;
typedef __attribute__((ext_vector_type(4))) float f32x4;
typedef __attribute__((ext_vector_type(4))) short short4v;

__device__ inline short f2bf(float f) {
  union { float f; unsigned u; } x; x.f = f;
  unsigned r = x.u + 0x7FFFu + ((x.u >> 16) & 1u);
  return (short)(r >> 16);
}

// ---------------------------------------------------------------------------
// Kernel 1: QKV projection via MFMA (unchanged from rounds 1-2).
// C[8192 x 192] = Xbf16[8192 x 1024] @ W^T. Q scaled by 1/32 (=1/sqrt(1024)).
// V stored transposed [b][64][2048] so flash PV is an NT GEMM.
// ---------------------------------------------------------------------------
__global__ __launch_bounds__(256) void proj_kernel(
    const float* __restrict__ X, const float* __restrict__ Wq,
    const float* __restrict__ Wk, const float* __restrict__ Wv,
    short* __restrict__ qout, short* __restrict__ kout,
    short* __restrict__ vtout)
{
  __shared__ short x_lds[64][72];   // 64 rows x 64 k (pad->72: 2-way free)
  __shared__ short w_lds[192][72];  // 192 cols x 64 k

  const int t = threadIdx.x;
  const int l = t & 63;
  const int w = t >> 6;
  const int m0 = blockIdx.x * 64;

  f32x4 acc[12];
#pragma unroll
  for (int i = 0; i < 12; i++) acc[i] = (f32x4){0.f, 0.f, 0.f, 0.f};

  const int r_x = t >> 2;          // 0..63
  const int c0 = (t & 3) * 16;     // 0/16/32/48

  for (int k0 = 0; k0 < DM; k0 += 64) {
    __syncthreads();
    // stage X tile (fp32 -> bf16)
    {
      const float* src = X + (size_t)(m0 + r_x) * DM + k0 + c0;
#pragma unroll
      for (int j = 0; j < 4; j++) {
        f32x4 f = ((const f32x4*)src)[j];
        short4v h = { f2bf(f[0]), f2bf(f[1]), f2bf(f[2]), f2bf(f[3]) };
        *(short4v*)&x_lds[r_x][c0 + j * 4] = h;
      }
    }
    // stage W tile (3 matrices stacked: rows 0-63 Wq, 64-127 Wk, 128-191 Wv)
    {
      const float* wptr[3] = {Wq, Wk, Wv};
#pragma unroll
      for (int mtx = 0; mtx < 3; mtx++) {
        const float* src = wptr[mtx] + (size_t)r_x * DM + k0 + c0;
#pragma unroll
        for (int j = 0; j < 4; j++) {
          f32x4 f = ((const f32x4*)src)[j];
          short4v h = { f2bf(f[0]), f2bf(f[1]), f2bf(f[2]), f2bf(f[3]) };
          *(short4v*)&w_lds[mtx * 64 + r_x][c0 + j * 4] = h;
        }
      }
    }
    __syncthreads();

    const short* xr = &x_lds[w * 16 + (l & 15)][(l >> 4) << 3];
    bf16x8 a0 = *(const bf16x8*)xr;
    bf16x8 a1 = *(const bf16x8*)(xr + 32);
#pragma unroll
    for (int nf = 0; nf < 12; nf++) {
      const short* wr = &w_lds[nf * 16 + (l & 15)][(l >> 4) << 3];
      bf16x8 b0 = *(const bf16x8*)wr;
      bf16x8 b1 = *(const bf16x8*)(wr + 32);
      acc[nf] = __builtin_amdgcn_mfma_f32_16x16x32_bf16(a0, b0, acc[nf], 0, 0, 0);
      acc[nf] = __builtin_amdgcn_mfma_f32_16x16x32_bf16(a1, b1, acc[nf], 0, 0, 0);
    }
  }

  // epilogue: C row = (lane>>4)*4 + reg, col = nf*16 + (lane&15)  [m89]
  const int rowb = m0 + w * 16 + ((l >> 4) << 2);
  const int cb = l & 15;
#pragma unroll
  for (int nf = 0; nf < 12; nf++) {
    const int c = nf * 16 + cb;
#pragma unroll
    for (int j = 0; j < 4; j++) {
      const int row = rowb + j;
      const float v = acc[nf][j];
      if (c < 64) {
        qout[row * DH + c] = f2bf(v * 0.03125f);  // fold 1/sqrt(d_model)=1/32
      } else if (c < 128) {
        kout[row * DH + (c - 64)] = f2bf(v);
      } else {
        const int b = row >> 11, s = row & (SEQ - 1);
        vtout[b * (DH * SEQ) + (c - 128) * SEQ + s] = f2bf(v);
      }
    }
  }
}

// ---------------------------------------------------------------------------
// Kernel 2: causal flash attention (round-1 design; epilogue now fp32).
// Block = (qtile of 64, batch), 4 waves x 16 q-rows. KV tiles of 64.
// Online softmax in registers; P bounced through per-wave padded LDS.
// ---------------------------------------------------------------------------
__global__ __launch_bounds__(256) void flash_kernel(
    const short* __restrict__ qin, const short* __restrict__ kin,
    const short* __restrict__ vtin, float* __restrict__ out)
{
  __shared__ short k_lds[64][72];       // [kv row][dh]
  __shared__ short vt_lds[64][72];      // [dh][kv row]  (already transposed)
  __shared__ short p_lds[4][16][72];    // per-wave P tile [qrow][kv]

  const int t = threadIdx.x;
  const int l = t & 63;
  const int w = t >> 6;
  const int qt = blockIdx.x;
  const int b  = blockIdx.y;
  const int q0 = qt * 64;

  const short* qb = qin  + (size_t)b * SEQ * DH;
  const short* kb = kin  + (size_t)b * SEQ * DH;
  const short* vb = vtin + (size_t)b * DH * SEQ;

  // Q fragments (rows fixed for the whole kv loop)
  const int lrow = w * 16 + (l & 15);
  const short* qr = qb + (size_t)(q0 + lrow) * DH + ((l >> 4) << 3);
  const bf16x8 qf0 = *(const bf16x8*)qr;
  const bf16x8 qf1 = *(const bf16x8*)(qr + 32);

  f32x4 o[4];
#pragma unroll
  for (int i = 0; i < 4; i++) o[i] = (f32x4){0.f, 0.f, 0.f, 0.f};
  float m_run[4] = {-1e30f, -1e30f, -1e30f, -1e30f};
  float l_run[4] = {0.f, 0.f, 0.f, 0.f};

  const int sr = t >> 3;          // 0..31
  const int sc = (t & 7) * 8;

  const int ntiles = qt + 1;
  for (int it = 0; it < ntiles; it++) {
    const int j0 = it * 64;
    __syncthreads();   // previous PV reads done before overwrite
#pragma unroll
    for (int i = 0; i < 2; i++) {
      const int r = sr + i * 32;
      bf16x8 kv = *(const bf16x8*)(kb + (size_t)(j0 + r) * DH + sc);
      *(bf16x8*)&k_lds[r][sc] = kv;
      bf16x8 vv = *(const bf16x8*)(vb + (size_t)r * SEQ + j0 + sc);
      *(bf16x8*)&vt_lds[r][sc] = vv;
    }
    __syncthreads();

    // S = Q K^T  (Q pre-scaled by 1/32)
    f32x4 s[4];
#pragma unroll
    for (int nf = 0; nf < 4; nf++) {
      const short* kr = &k_lds[nf * 16 + (l & 15)][(l >> 4) << 3];
      bf16x8 b0 = *(const bf16x8*)kr;
      bf16x8 b1 = *(const bf16x8*)(kr + 32);
      f32x4 a = (f32x4){0.f, 0.f, 0.f, 0.f};
      a = __builtin_amdgcn_mfma_f32_16x16x32_bf16(qf0, b0, a, 0, 0, 0);
      a = __builtin_amdgcn_mfma_f32_16x16x32_bf16(qf1, b1, a, 0, 0, 0);
      s[nf] = a;
    }

    // causal mask — only the diagonal tile is partial
    if (it == ntiles - 1) {
      const int growb = q0 + w * 16 + ((l >> 4) << 2);
#pragma unroll
      for (int nf = 0; nf < 4; nf++) {
        const int gcol = j0 + nf * 16 + (l & 15);
#pragma unroll
        for (int j = 0; j < 4; j++)
          if (gcol > growb + j) s[nf][j] = -1e30f;
      }
    }

    // online softmax (row R = (l>>4)*4+j lives across the 16-lane group)
    float alpha[4];
#pragma unroll
    for (int j = 0; j < 4; j++) {
      float tm = fmaxf(fmaxf(s[0][j], s[1][j]), fmaxf(s[2][j], s[3][j]));
      tm = fmaxf(tm, __shfl_xor(tm, 1));
      tm = fmaxf(tm, __shfl_xor(tm, 2));
      tm = fmaxf(tm, __shfl_xor(tm, 4));
      tm = fmaxf(tm, __shfl_xor(tm, 8));
      const float mn = fmaxf(m_run[j], tm);
      alpha[j] = exp2f((m_run[j] - mn) * 1.44269504f);
      m_run[j] = mn;
      float rs = 0.f;
#pragma unroll
      for (int nf = 0; nf < 4; nf++) {
        const float p = exp2f((s[nf][j] - mn) * 1.44269504f);
        s[nf][j] = p;
        rs += p;
      }
      rs += __shfl_xor(rs, 1);
      rs += __shfl_xor(rs, 2);
      rs += __shfl_xor(rs, 4);
      rs += __shfl_xor(rs, 8);
      l_run[j] = l_run[j] * alpha[j] + rs;
    }
#pragma unroll
    for (int df = 0; df < 4; df++)
#pragma unroll
      for (int j = 0; j < 4; j++) o[df][j] *= alpha[j];

    // P -> per-wave LDS (bf16), then PV
#pragma unroll
    for (int nf = 0; nf < 4; nf++)
#pragma unroll
      for (int j = 0; j < 4; j++)
        p_lds[w][((l >> 4) << 2) + j][nf * 16 + (l & 15)] = f2bf(s[nf][j]);

    asm volatile("s_waitcnt lgkmcnt(0)" ::: "memory");
    __builtin_amdgcn_sched_barrier(0);

#pragma unroll
    for (int ks = 0; ks < 2; ks++) {
      const short* pr = &p_lds[w][l & 15][ks * 32 + ((l >> 4) << 3)];
      const bf16x8 pa = *(const bf16x8*)pr;
#pragma unroll
      for (int df = 0; df < 4; df++) {
        const short* vr = &vt_lds[df * 16 + (l & 15)][ks * 32 + ((l >> 4) << 3)];
        const bf16x8 vf = *(const bf16x8*)vr;
        o[df] = __builtin_amdgcn_mfma_f32_16x16x32_bf16(pa, vf, o[df], 0, 0, 0);
      }
    }
  }

  // epilogue — fp32 output (reference output dtype is float32!)
  float* ob = out + (size_t)b * SEQ * DH;
  const int rowb = q0 + w * 16 + ((l >> 4) << 2);
#pragma unroll
  for (int j = 0; j < 4; j++) {
    const float inv = 1.0f / l_run[j];
#pragma unroll
    for (int df = 0; df < 4; df++)
      ob[(size_t)(rowb + j) * DH + df * 16 + (l & 15)] = o[df][j] * inv;
  }
}

extern "C" void kernel_launch(void* const* d_in, const int* in_sizes, int n_in,
                              void* d_out, int out_size, void* d_ws, size_t ws_size,
                              hipStream_t stream) {
  const float* X  = (const float*)d_in[0];
  const float* Wq = (const float*)d_in[1];
  const float* Wk = (const float*)d_in[2];
  const float* Wv = (const float*)d_in[3];

  short* qws  = (short*)d_ws;                    // [8192][64] bf16, pre-scaled
  short* kws  = qws + (size_t)NB * SEQ * DH;     // [8192][64] bf16
  short* vtws = kws + (size_t)NB * SEQ * DH;     // [4][64][2048] bf16 (V^T)

  proj_kernel<<<dim3(NB * SEQ / 64), 256, 0, stream>>>(X, Wq, Wk, Wv, qws, kws, vtws);
  flash_kernel<<<dim3(SEQ / 64, NB), 256, 0, stream>>>(qws, kws, vtws, (float*)d_out);
}

// Round 6
// 65.072 us; speedup vs baseline: 2.1168x; 2.1168x over previous
//
#include <hip/hip_runtime.h>
#include <hip/hip_bf16.h>

// Problem constants
#define NB 4
#define SEQ 2048
#define DM 1024
#define DH 64

typedef __attribute__((ext_vector_type(8))) short bf16x8;
typedef __attribute__((ext_vector_type(4))) float f32x4;
typedef __attribute__((ext_vector_type(4))) short short4v;

__device__ inline short f2bf(float f) {
  union { float f; unsigned u; } x; x.f = f;
  unsigned r = x.u + 0x7FFFu + ((x.u >> 16) & 1u);
  return (short)(r >> 16);
}

// ---------------------------------------------------------------------------
// Kernel 1: QKV projection. 256 blocks x 512 threads (8 waves = 2/SIMD).
// Block tile: 32 rows x 192 cols. Wave w: row-frag (w&1), col-frags (w>>1)*3+.
// ---------------------------------------------------------------------------
__global__ __launch_bounds__(512) void proj_kernel(
    const float* __restrict__ X, const float* __restrict__ Wq,
    const float* __restrict__ Wk, const float* __restrict__ Wv,
    short* __restrict__ qout, short* __restrict__ kout,
    short* __restrict__ vtout)
{
  __shared__ short x_lds[32][72];
  __shared__ short w_lds[192][72];

  const int t = threadIdx.x;
  const int l = t & 63;
  const int w = t >> 6;            // 0..7
  const int m0 = blockIdx.x * 32;

  f32x4 acc[3];
#pragma unroll
  for (int i = 0; i < 3; i++) acc[i] = (f32x4){0.f, 0.f, 0.f, 0.f};

  const int xr = t >> 4;           // 0..31
  const int xc = (t & 15) * 4;     // 0..60
  const int wr = t >> 3;           // 0..63
  const int wc = (t & 7) * 8;      // 0..56

  for (int k0 = 0; k0 < DM; k0 += 64) {
    __syncthreads();
    {
      f32x4 f = *(const f32x4*)(X + (size_t)(m0 + xr) * DM + k0 + xc);
      short4v h = { f2bf(f[0]), f2bf(f[1]), f2bf(f[2]), f2bf(f[3]) };
      *(short4v*)&x_lds[xr][xc] = h;
    }
    {
      const float* wptr[3] = {Wq, Wk, Wv};
#pragma unroll
      for (int mtx = 0; mtx < 3; mtx++) {
        const float* src = wptr[mtx] + (size_t)wr * DM + k0 + wc;
#pragma unroll
        for (int j = 0; j < 2; j++) {
          f32x4 f = ((const f32x4*)src)[j];
          short4v h = { f2bf(f[0]), f2bf(f[1]), f2bf(f[2]), f2bf(f[3]) };
          *(short4v*)&w_lds[mtx * 64 + wr][wc + j * 4] = h;
        }
      }
    }
    __syncthreads();

    const short* xp = &x_lds[(w & 1) * 16 + (l & 15)][(l >> 4) << 3];
    bf16x8 a0 = *(const bf16x8*)xp;
    bf16x8 a1 = *(const bf16x8*)(xp + 32);
#pragma unroll
    for (int nf = 0; nf < 3; nf++) {
      const int cf = (w >> 1) * 3 + nf;
      const short* wp = &w_lds[cf * 16 + (l & 15)][(l >> 4) << 3];
      bf16x8 b0 = *(const bf16x8*)wp;
      bf16x8 b1 = *(const bf16x8*)(wp + 32);
      acc[nf] = __builtin_amdgcn_mfma_f32_16x16x32_bf16(a0, b0, acc[nf], 0, 0, 0);
      acc[nf] = __builtin_amdgcn_mfma_f32_16x16x32_bf16(a1, b1, acc[nf], 0, 0, 0);
    }
  }

  // epilogue: C row=(lane>>4)*4+reg, col=cf*16+(lane&15)  [m89]
  const int rowb = m0 + (w & 1) * 16 + ((l >> 4) << 2);
#pragma unroll
  for (int nf = 0; nf < 3; nf++) {
    const int c = ((w >> 1) * 3 + nf) * 16 + (l & 15);
#pragma unroll
    for (int j = 0; j < 4; j++) {
      const int row = rowb + j;
      const float v = acc[nf][j];
      if (c < 64) {
        qout[row * DH + c] = f2bf(v * 0.03125f);  // fold 1/sqrt(1024)=1/32
      } else if (c < 128) {
        kout[row * DH + (c - 64)] = f2bf(v);
      } else {
        const int b = row >> 11, s = row & (SEQ - 1);
        vtout[b * (DH * SEQ) + (c - 128) * SEQ + s] = f2bf(v);
      }
    }
  }
}

// ---------------------------------------------------------------------------
// Kernel 2: split-KV causal flash. Grid (qt, nck, b); nck/cht are runtime
// (ws-size-dependent). Block = 4 waves x 16 q-rows over a 64-row qtile;
// processes <=cht KV tiles with double-buffered LDS + reg prefetch.
// Writes unnormalized partials (o, m, l) per row/chunk to ws.
// ---------------------------------------------------------------------------
__global__ __launch_bounds__(256) void flash_kernel(
    const short* __restrict__ qin, const short* __restrict__ kin,
    const short* __restrict__ vtin, float* __restrict__ po,
    float* __restrict__ pm, float* __restrict__ pl,
    const int nck, const int cht)
{
  __shared__ short k_lds[2][64][72];
  __shared__ short vt_lds[2][64][72];
  __shared__ short p_lds[4][16][72];

  const int qt = blockIdx.x;
  const int ck = blockIdx.y;
  const int t0 = ck * cht;
  if (t0 > qt) return;                        // inactive (beyond causal range)
  const int b = blockIdx.z;

  const int t = threadIdx.x;
  const int l = t & 63;
  const int w = t >> 6;
  const int q0 = qt * 64;
  const int tend = min(t0 + cht, qt + 1);

  const short* qb = qin  + (size_t)b * SEQ * DH;
  const short* kb = kin  + (size_t)b * SEQ * DH;
  const short* vb = vtin + (size_t)b * DH * SEQ;

  // Q fragments (fixed rows)
  const short* qr = qb + (size_t)(q0 + w * 16 + (l & 15)) * DH + ((l >> 4) << 3);
  const bf16x8 qf0 = *(const bf16x8*)qr;
  const bf16x8 qf1 = *(const bf16x8*)(qr + 32);

  f32x4 o[4];
#pragma unroll
  for (int i = 0; i < 4; i++) o[i] = (f32x4){0.f, 0.f, 0.f, 0.f};
  float m_run[4] = {-1e30f, -1e30f, -1e30f, -1e30f};
  float l_run[4] = {0.f, 0.f, 0.f, 0.f};

  const int sr = t >> 3;           // 0..31
  const int sc = (t & 7) * 8;

  // prologue: stage tile t0 into buffer 0
  {
    const int j0 = t0 * 64;
#pragma unroll
    for (int i = 0; i < 2; i++) {
      const int r = sr + i * 32;
      *(bf16x8*)&k_lds[0][r][sc]  = *(const bf16x8*)(kb + (size_t)(j0 + r) * DH + sc);
      *(bf16x8*)&vt_lds[0][r][sc] = *(const bf16x8*)(vb + (size_t)r * SEQ + j0 + sc);
    }
  }
  __syncthreads();

  for (int tt = t0; tt < tend; tt++) {
    const int bi = (tt - t0) & 1;
    const int j0 = tt * 64;
    const bool pf = (tt + 1 < tend);

    // issue prefetch loads for tile tt+1 (regs; consumed after compute)
    bf16x8 kpf0, kpf1, vpf0, vpf1;
    if (pf) {
      const int j1 = j0 + 64;
      kpf0 = *(const bf16x8*)(kb + (size_t)(j1 + sr) * DH + sc);
      kpf1 = *(const bf16x8*)(kb + (size_t)(j1 + sr + 32) * DH + sc);
      vpf0 = *(const bf16x8*)(vb + (size_t)sr * SEQ + j1 + sc);
      vpf1 = *(const bf16x8*)(vb + (size_t)(sr + 32) * SEQ + j1 + sc);
    }

    // S = Q K^T  (Q pre-scaled by 1/32)
    f32x4 s[4];
#pragma unroll
    for (int nf = 0; nf < 4; nf++) {
      const short* kr = &k_lds[bi][nf * 16 + (l & 15)][(l >> 4) << 3];
      bf16x8 b0 = *(const bf16x8*)kr;
      bf16x8 b1 = *(const bf16x8*)(kr + 32);
      f32x4 a = (f32x4){0.f, 0.f, 0.f, 0.f};
      a = __builtin_amdgcn_mfma_f32_16x16x32_bf16(qf0, b0, a, 0, 0, 0);
      a = __builtin_amdgcn_mfma_f32_16x16x32_bf16(qf1, b1, a, 0, 0, 0);
      s[nf] = a;
    }

    // causal mask
    {
      const int growb = q0 + w * 16 + ((l >> 4) << 2);
#pragma unroll
      for (int nf = 0; nf < 4; nf++) {
        const int gcol = j0 + nf * 16 + (l & 15);
#pragma unroll
        for (int j = 0; j < 4; j++)
          if (gcol > growb + j) s[nf][j] = -1e30f;
      }
    }

    // online softmax
    float alpha[4];
#pragma unroll
    for (int j = 0; j < 4; j++) {
      float tm = fmaxf(fmaxf(s[0][j], s[1][j]), fmaxf(s[2][j], s[3][j]));
      tm = fmaxf(tm, __shfl_xor(tm, 1));
      tm = fmaxf(tm, __shfl_xor(tm, 2));
      tm = fmaxf(tm, __shfl_xor(tm, 4));
      tm = fmaxf(tm, __shfl_xor(tm, 8));
      const float mn = fmaxf(m_run[j], tm);
      alpha[j] = exp2f((m_run[j] - mn) * 1.44269504f);
      m_run[j] = mn;
      float rs = 0.f;
#pragma unroll
      for (int nf = 0; nf < 4; nf++) {
        const float p = exp2f((s[nf][j] - mn) * 1.44269504f);
        s[nf][j] = p;
        rs += p;
      }
      rs += __shfl_xor(rs, 1);
      rs += __shfl_xor(rs, 2);
      rs += __shfl_xor(rs, 4);
      rs += __shfl_xor(rs, 8);
      l_run[j] = l_run[j] * alpha[j] + rs;
    }
#pragma unroll
    for (int df = 0; df < 4; df++)
#pragma unroll
      for (int j = 0; j < 4; j++) o[df][j] *= alpha[j];

    // P -> per-wave LDS (bf16), then PV
#pragma unroll
    for (int nf = 0; nf < 4; nf++)
#pragma unroll
      for (int j = 0; j < 4; j++)
        p_lds[w][((l >> 4) << 2) + j][nf * 16 + (l & 15)] = f2bf(s[nf][j]);

    asm volatile("s_waitcnt lgkmcnt(0)" ::: "memory");
    __builtin_amdgcn_sched_barrier(0);

#pragma unroll
    for (int ks = 0; ks < 2; ks++) {
      const short* pr = &p_lds[w][l & 15][ks * 32 + ((l >> 4) << 3)];
      const bf16x8 pa = *(const bf16x8*)pr;
#pragma unroll
      for (int df = 0; df < 4; df++) {
        const short* vr = &vt_lds[bi][df * 16 + (l & 15)][ks * 32 + ((l >> 4) << 3)];
        const bf16x8 vf = *(const bf16x8*)vr;
        o[df] = __builtin_amdgcn_mfma_f32_16x16x32_bf16(pa, vf, o[df], 0, 0, 0);
      }
    }

    // write prefetched tile into the other buffer, one barrier per iter
    if (pf) {
      *(bf16x8*)&k_lds[bi ^ 1][sr][sc]       = kpf0;
      *(bf16x8*)&k_lds[bi ^ 1][sr + 32][sc]  = kpf1;
      *(bf16x8*)&vt_lds[bi ^ 1][sr][sc]      = vpf0;
      *(bf16x8*)&vt_lds[bi ^ 1][sr + 32][sc] = vpf1;
    }
    __syncthreads();
  }

  // epilogue: unnormalized partials
  const int rowb = q0 + w * 16 + ((l >> 4) << 2);
#pragma unroll
  for (int j = 0; j < 4; j++) {
    const size_t rowg = (size_t)b * SEQ + rowb + j;
#pragma unroll
    for (int df = 0; df < 4; df++)
      po[(rowg * nck + ck) * DH + df * 16 + (l & 15)] = o[df][j];
    if ((l & 15) == 0) {
      pm[rowg * nck + ck] = m_run[j];
      pl[rowg * nck + ck] = l_run[j];
    }
  }
}

// ---------------------------------------------------------------------------
// Kernel 3: merge partials. Thread per (row, dh). ckshift = log2(cht*64).
// ---------------------------------------------------------------------------
__global__ __launch_bounds__(256) void merge_kernel(
    const float* __restrict__ po, const float* __restrict__ pm,
    const float* __restrict__ pl, float* __restrict__ out,
    const int nck, const int ckshift)
{
  const int gid = blockIdx.x * 256 + threadIdx.x;   // 0..524287
  const int r = gid >> 6;
  const int d = gid & 63;
  const int s = r & (SEQ - 1);
  const int C = (s >> ckshift) + 1;                  // chunks covering [0,s]

  float m = -1e30f;
  for (int c = 0; c < C; c++) m = fmaxf(m, pm[r * nck + c]);
  float den = 0.f, num = 0.f;
  for (int c = 0; c < C; c++) {
    const float wgt = exp2f((pm[r * nck + c] - m) * 1.44269504f);
    den += pl[r * nck + c] * wgt;
    num += po[(size_t)(r * nck + c) * DH + d] * wgt;
  }
  out[gid] = num / den;
}

extern "C" void kernel_launch(void* const* d_in, const int* in_sizes, int n_in,
                              void* d_out, int out_size, void* d_ws, size_t ws_size,
                              hipStream_t stream) {
  const float* X  = (const float*)d_in[0];
  const float* Wq = (const float*)d_in[1];
  const float* Wk = (const float*)d_in[2];
  const float* Wv = (const float*)d_in[3];

  const size_t nrow = (size_t)NB * SEQ;              // 8192
  short* qws  = (short*)d_ws;                        // [8192][64] bf16
  short* kws  = qws + nrow * DH;                     // [8192][64] bf16
  short* vtws = kws + nrow * DH;                     // [4][64][2048] bf16 (V^T)
  float* po   = (float*)(vtws + nrow * DH);          // [8192][nck][64] f32
  const size_t qkv_bytes = 3 * nrow * DH * sizeof(short);

  // choose chunk count by available workspace (defensive vs ws overflow)
  int nck, cht, ckshift;
  {
    const size_t need4 = qkv_bytes + nrow * 4 * (DH + 2) * sizeof(float);
    if (ws_size >= need4) { nck = 4; cht = 8;  ckshift = 9;  }
    else                  { nck = 1; cht = 32; ckshift = 11; }
  }
  float* pm = po + nrow * nck * DH;                  // [8192][nck]
  float* pl = pm + nrow * nck;                       // [8192][nck]

  proj_kernel<<<dim3(NB * SEQ / 32), 512, 0, stream>>>(X, Wq, Wk, Wv, qws, kws, vtws);
  flash_kernel<<<dim3(SEQ / 64, nck, NB), 256, 0, stream>>>(qws, kws, vtws, po, pm, pl, nck, cht);
  merge_kernel<<<dim3(NB * SEQ * DH / 256), 256, 0, stream>>>(po, pm, pl, (float*)d_out, nck, ckshift);
}

// Round 7
// 52.882 us; speedup vs baseline: 2.6048x; 1.2305x over previous
//
#include <hip/hip_runtime.h>
#include <hip/hip_bf16.h>

// Problem constants
#define NB 4
#define SEQ 2048
#define DM 1024
#define DH 64

typedef __attribute__((ext_vector_type(8))) short bf16x8;
typedef __attribute__((ext_vector_type(4))) float f32x4;
typedef __attribute__((ext_vector_type(4))) short short4v;

__device__ inline short f2bf(float f) {
  union { float f; unsigned u; } x; x.f = f;
  unsigned r = x.u + 0x7FFFu + ((x.u >> 16) & 1u);
  return (short)(r >> 16);
}

// ---------------------------------------------------------------------------
// Kernel 0: W fp32 -> bf16, once. wbf[192][1024]: rows 0-63 Wq, 64-127 Wk,
// 128-191 Wv. 96 blocks x 256 threads x 8 elements.
// ---------------------------------------------------------------------------
__global__ __launch_bounds__(256) void wconv_kernel(
    const float* __restrict__ Wq, const float* __restrict__ Wk,
    const float* __restrict__ Wv, short* __restrict__ wbf)
{
  const int tid = blockIdx.x * 256 + threadIdx.x;
  const int base = tid * 8;
  const int row = base >> 10;          // 0..191
  const int col = base & 1023;
  const float* src = (row < 64) ? Wq : (row < 128) ? Wk : Wv;
  src += (size_t)(row & 63) * DM + col;
  f32x4 f0 = ((const f32x4*)src)[0];
  f32x4 f1 = ((const f32x4*)src)[1];
  bf16x8 h = { f2bf(f0[0]), f2bf(f0[1]), f2bf(f0[2]), f2bf(f0[3]),
               f2bf(f1[0]), f2bf(f1[1]), f2bf(f1[2]), f2bf(f1[3]) };
  *(bf16x8*)(wbf + (size_t)row * DM + col) = h;
}

// ---------------------------------------------------------------------------
// Kernel 1: QKV projection. 256 blocks x 512 threads, 32-row x 192-col tile.
// Double-buffered LDS + reg prefetch (flash-proven pattern), one barrier/iter.
// W staged as bf16 (preconverted). Q scaled 1/32; V stored transposed.
// ---------------------------------------------------------------------------
__global__ __launch_bounds__(512) void proj_kernel(
    const float* __restrict__ X, const short* __restrict__ wbf,
    short* __restrict__ qout, short* __restrict__ kout,
    short* __restrict__ vtout)
{
  __shared__ short x_lds[2][32][80];    // stride 80 shorts = 40 dwords
  __shared__ short w_lds[2][192][80];

  const int t = threadIdx.x;
  const int l = t & 63;
  const int w = t >> 6;                 // 0..7
  const int m0 = blockIdx.x * 32;

  f32x4 acc[3];
#pragma unroll
  for (int i = 0; i < 3; i++) acc[i] = (f32x4){0.f, 0.f, 0.f, 0.f};

  const int xr = t >> 4;                // 0..31
  const int xc = (t & 15) * 4;          // float cols 0..60
  const int wr = t >> 3;                // 0..63
  const int wc = (t & 7) * 8;           // bf16 cols 0..56

  // prologue: stage k0=0 into buffer 0
  {
    f32x4 f = *(const f32x4*)(X + (size_t)(m0 + xr) * DM + xc);
    short4v h = { f2bf(f[0]), f2bf(f[1]), f2bf(f[2]), f2bf(f[3]) };
    *(short4v*)&x_lds[0][xr][xc] = h;
#pragma unroll
    for (int s = 0; s < 3; s++)
      *(bf16x8*)&w_lds[0][s * 64 + wr][wc] =
          *(const bf16x8*)(wbf + (size_t)(s * 64 + wr) * DM + wc);
  }
  __syncthreads();

  for (int it = 0; it < 16; it++) {
    const int buf = it & 1;
    const bool pf = (it < 15);

    // issue prefetch loads for iter it+1 (consumed after compute)
    f32x4 xf;
    bf16x8 wf0, wf1, wf2;
    if (pf) {
      const int k1 = (it + 1) * 64;
      xf  = *(const f32x4*)(X + (size_t)(m0 + xr) * DM + k1 + xc);
      wf0 = *(const bf16x8*)(wbf + (size_t)(0 * 64 + wr) * DM + k1 + wc);
      wf1 = *(const bf16x8*)(wbf + (size_t)(1 * 64 + wr) * DM + k1 + wc);
      wf2 = *(const bf16x8*)(wbf + (size_t)(2 * 64 + wr) * DM + k1 + wc);
    }

    // compute from lds[buf]
    const short* xp = &x_lds[buf][(w & 1) * 16 + (l & 15)][(l >> 4) << 3];
    bf16x8 a0 = *(const bf16x8*)xp;
    bf16x8 a1 = *(const bf16x8*)(xp + 32);
#pragma unroll
    for (int nf = 0; nf < 3; nf++) {
      const int cf = (w >> 1) * 3 + nf;
      const short* wp = &w_lds[buf][cf * 16 + (l & 15)][(l >> 4) << 3];
      bf16x8 b0 = *(const bf16x8*)wp;
      bf16x8 b1 = *(const bf16x8*)(wp + 32);
      acc[nf] = __builtin_amdgcn_mfma_f32_16x16x32_bf16(a0, b0, acc[nf], 0, 0, 0);
      acc[nf] = __builtin_amdgcn_mfma_f32_16x16x32_bf16(a1, b1, acc[nf], 0, 0, 0);
    }

    // write prefetched tile into the other buffer, one barrier per iter
    if (pf) {
      short4v h = { f2bf(xf[0]), f2bf(xf[1]), f2bf(xf[2]), f2bf(xf[3]) };
      *(short4v*)&x_lds[buf ^ 1][xr][xc] = h;
      *(bf16x8*)&w_lds[buf ^ 1][0 * 64 + wr][wc] = wf0;
      *(bf16x8*)&w_lds[buf ^ 1][1 * 64 + wr][wc] = wf1;
      *(bf16x8*)&w_lds[buf ^ 1][2 * 64 + wr][wc] = wf2;
    }
    __syncthreads();
  }

  // epilogue: C row=(lane>>4)*4+reg, col=cf*16+(lane&15)  [m89]
  const int rowb = m0 + (w & 1) * 16 + ((l >> 4) << 2);
#pragma unroll
  for (int nf = 0; nf < 3; nf++) {
    const int c = ((w >> 1) * 3 + nf) * 16 + (l & 15);
#pragma unroll
    for (int j = 0; j < 4; j++) {
      const int row = rowb + j;
      const float v = acc[nf][j];
      if (c < 64) {
        qout[row * DH + c] = f2bf(v * 0.03125f);  // fold 1/sqrt(1024)=1/32
      } else if (c < 128) {
        kout[row * DH + (c - 64)] = f2bf(v);
      } else {
        const int b = row >> 11, s = row & (SEQ - 1);
        vtout[b * (DH * SEQ) + (c - 128) * SEQ + s] = f2bf(v);
      }
    }
  }
}

// ---------------------------------------------------------------------------
// Kernel 2: split-KV causal flash (unchanged from round 6).
// ---------------------------------------------------------------------------
__global__ __launch_bounds__(256) void flash_kernel(
    const short* __restrict__ qin, const short* __restrict__ kin,
    const short* __restrict__ vtin, float* __restrict__ po,
    float* __restrict__ pm, float* __restrict__ pl,
    const int nck, const int cht)
{
  __shared__ short k_lds[2][64][72];
  __shared__ short vt_lds[2][64][72];
  __shared__ short p_lds[4][16][72];

  const int qt = blockIdx.x;
  const int ck = blockIdx.y;
  const int t0 = ck * cht;
  if (t0 > qt) return;
  const int b = blockIdx.z;

  const int t = threadIdx.x;
  const int l = t & 63;
  const int w = t >> 6;
  const int q0 = qt * 64;
  const int tend = min(t0 + cht, qt + 1);

  const short* qb = qin  + (size_t)b * SEQ * DH;
  const short* kb = kin  + (size_t)b * SEQ * DH;
  const short* vb = vtin + (size_t)b * DH * SEQ;

  const short* qr = qb + (size_t)(q0 + w * 16 + (l & 15)) * DH + ((l >> 4) << 3);
  const bf16x8 qf0 = *(const bf16x8*)qr;
  const bf16x8 qf1 = *(const bf16x8*)(qr + 32);

  f32x4 o[4];
#pragma unroll
  for (int i = 0; i < 4; i++) o[i] = (f32x4){0.f, 0.f, 0.f, 0.f};
  float m_run[4] = {-1e30f, -1e30f, -1e30f, -1e30f};
  float l_run[4] = {0.f, 0.f, 0.f, 0.f};

  const int sr = t >> 3;
  const int sc = (t & 7) * 8;

  {
    const int j0 = t0 * 64;
#pragma unroll
    for (int i = 0; i < 2; i++) {
      const int r = sr + i * 32;
      *(bf16x8*)&k_lds[0][r][sc]  = *(const bf16x8*)(kb + (size_t)(j0 + r) * DH + sc);
      *(bf16x8*)&vt_lds[0][r][sc] = *(const bf16x8*)(vb + (size_t)r * SEQ + j0 + sc);
    }
  }
  __syncthreads();

  for (int tt = t0; tt < tend; tt++) {
    const int bi = (tt - t0) & 1;
    const int j0 = tt * 64;
    const bool pf = (tt + 1 < tend);

    bf16x8 kpf0, kpf1, vpf0, vpf1;
    if (pf) {
      const int j1 = j0 + 64;
      kpf0 = *(const bf16x8*)(kb + (size_t)(j1 + sr) * DH + sc);
      kpf1 = *(const bf16x8*)(kb + (size_t)(j1 + sr + 32) * DH + sc);
      vpf0 = *(const bf16x8*)(vb + (size_t)sr * SEQ + j1 + sc);
      vpf1 = *(const bf16x8*)(vb + (size_t)(sr + 32) * SEQ + j1 + sc);
    }

    f32x4 s[4];
#pragma unroll
    for (int nf = 0; nf < 4; nf++) {
      const short* kr = &k_lds[bi][nf * 16 + (l & 15)][(l >> 4) << 3];
      bf16x8 b0 = *(const bf16x8*)kr;
      bf16x8 b1 = *(const bf16x8*)(kr + 32);
      f32x4 a = (f32x4){0.f, 0.f, 0.f, 0.f};
      a = __builtin_amdgcn_mfma_f32_16x16x32_bf16(qf0, b0, a, 0, 0, 0);
      a = __builtin_amdgcn_mfma_f32_16x16x32_bf16(qf1, b1, a, 0, 0, 0);
      s[nf] = a;
    }

    {
      const int growb = q0 + w * 16 + ((l >> 4) << 2);
#pragma unroll
      for (int nf = 0; nf < 4; nf++) {
        const int gcol = j0 + nf * 16 + (l & 15);
#pragma unroll
        for (int j = 0; j < 4; j++)
          if (gcol > growb + j) s[nf][j] = -1e30f;
      }
    }

    float alpha[4];
#pragma unroll
    for (int j = 0; j < 4; j++) {
      float tm = fmaxf(fmaxf(s[0][j], s[1][j]), fmaxf(s[2][j], s[3][j]));
      tm = fmaxf(tm, __shfl_xor(tm, 1));
      tm = fmaxf(tm, __shfl_xor(tm, 2));
      tm = fmaxf(tm, __shfl_xor(tm, 4));
      tm = fmaxf(tm, __shfl_xor(tm, 8));
      const float mn = fmaxf(m_run[j], tm);
      alpha[j] = exp2f((m_run[j] - mn) * 1.44269504f);
      m_run[j] = mn;
      float rs = 0.f;
#pragma unroll
      for (int nf = 0; nf < 4; nf++) {
        const float p = exp2f((s[nf][j] - mn) * 1.44269504f);
        s[nf][j] = p;
        rs += p;
      }
      rs += __shfl_xor(rs, 1);
      rs += __shfl_xor(rs, 2);
      rs += __shfl_xor(rs, 4);
      rs += __shfl_xor(rs, 8);
      l_run[j] = l_run[j] * alpha[j] + rs;
    }
#pragma unroll
    for (int df = 0; df < 4; df++)
#pragma unroll
      for (int j = 0; j < 4; j++) o[df][j] *= alpha[j];

#pragma unroll
    for (int nf = 0; nf < 4; nf++)
#pragma unroll
      for (int j = 0; j < 4; j++)
        p_lds[w][((l >> 4) << 2) + j][nf * 16 + (l & 15)] = f2bf(s[nf][j]);

    asm volatile("s_waitcnt lgkmcnt(0)" ::: "memory");
    __builtin_amdgcn_sched_barrier(0);

#pragma unroll
    for (int ks = 0; ks < 2; ks++) {
      const short* pr = &p_lds[w][l & 15][ks * 32 + ((l >> 4) << 3)];
      const bf16x8 pa = *(const bf16x8*)pr;
#pragma unroll
      for (int df = 0; df < 4; df++) {
        const short* vr = &vt_lds[bi][df * 16 + (l & 15)][ks * 32 + ((l >> 4) << 3)];
        const bf16x8 vf = *(const bf16x8*)vr;
        o[df] = __builtin_amdgcn_mfma_f32_16x16x32_bf16(pa, vf, o[df], 0, 0, 0);
      }
    }

    if (pf) {
      *(bf16x8*)&k_lds[bi ^ 1][sr][sc]       = kpf0;
      *(bf16x8*)&k_lds[bi ^ 1][sr + 32][sc]  = kpf1;
      *(bf16x8*)&vt_lds[bi ^ 1][sr][sc]      = vpf0;
      *(bf16x8*)&vt_lds[bi ^ 1][sr + 32][sc] = vpf1;
    }
    __syncthreads();
  }

  const int rowb = q0 + w * 16 + ((l >> 4) << 2);
#pragma unroll
  for (int j = 0; j < 4; j++) {
    const size_t rowg = (size_t)b * SEQ + rowb + j;
#pragma unroll
    for (int df = 0; df < 4; df++)
      po[(rowg * nck + ck) * DH + df * 16 + (l & 15)] = o[df][j];
    if ((l & 15) == 0) {
      pm[rowg * nck + ck] = m_run[j];
      pl[rowg * nck + ck] = l_run[j];
    }
  }
}

// ---------------------------------------------------------------------------
// Kernel 3: merge partials (unchanged from round 6).
// ---------------------------------------------------------------------------
__global__ __launch_bounds__(256) void merge_kernel(
    const float* __restrict__ po, const float* __restrict__ pm,
    const float* __restrict__ pl, float* __restrict__ out,
    const int nck, const int ckshift)
{
  const int gid = blockIdx.x * 256 + threadIdx.x;
  const int r = gid >> 6;
  const int d = gid & 63;
  const int s = r & (SEQ - 1);
  const int C = (s >> ckshift) + 1;

  float m = -1e30f;
  for (int c = 0; c < C; c++) m = fmaxf(m, pm[r * nck + c]);
  float den = 0.f, num = 0.f;
  for (int c = 0; c < C; c++) {
    const float wgt = exp2f((pm[r * nck + c] - m) * 1.44269504f);
    den += pl[r * nck + c] * wgt;
    num += po[(size_t)(r * nck + c) * DH + d] * wgt;
  }
  out[gid] = num / den;
}

extern "C" void kernel_launch(void* const* d_in, const int* in_sizes, int n_in,
                              void* d_out, int out_size, void* d_ws, size_t ws_size,
                              hipStream_t stream) {
  const float* X  = (const float*)d_in[0];
  const float* Wq = (const float*)d_in[1];
  const float* Wk = (const float*)d_in[2];
  const float* Wv = (const float*)d_in[3];

  const size_t nrow = (size_t)NB * SEQ;              // 8192
  short* qws  = (short*)d_ws;                        // [8192][64] bf16
  short* kws  = qws + nrow * DH;                     // [8192][64] bf16
  short* vtws = kws + nrow * DH;                     // [4][64][2048] bf16 (V^T)
  float* po   = (float*)(vtws + nrow * DH);          // [8192][nck][64] f32
  // wbf ALIASES the po region: wconv writes it, proj reads it, then flash
  // overwrites with po. Sequential on stream + rewritten every call -> safe.
  short* wbf  = (short*)po;                          // [192][1024] bf16
  const size_t qkv_bytes = 3 * nrow * DH * sizeof(short);

  int nck, cht, ckshift;
  {
    const size_t need4 = qkv_bytes + nrow * 4 * (DH + 2) * sizeof(float);
    if (ws_size >= need4) { nck = 4; cht = 8;  ckshift = 9;  }
    else                  { nck = 1; cht = 32; ckshift = 11; }
  }
  float* pm = po + nrow * nck * DH;
  float* pl = pm + nrow * nck;

  wconv_kernel<<<dim3(96), 256, 0, stream>>>(Wq, Wk, Wv, wbf);
  proj_kernel<<<dim3(NB * SEQ / 32), 512, 0, stream>>>(X, wbf, qws, kws, vtws);
  flash_kernel<<<dim3(SEQ / 64, nck, NB), 256, 0, stream>>>(qws, kws, vtws, po, pm, pl, nck, cht);
  merge_kernel<<<dim3(NB * SEQ * DH / 256), 256, 0, stream>>>(po, pm, pl, (float*)d_out, nck, ckshift);
}

// Round 9
// 48.480 us; speedup vs baseline: 2.8413x; 1.0908x over previous
//
#include <hip/hip_runtime.h>
#include <hip/hip_bf16.h>

// Problem constants
#define NB 4
#define SEQ 2048
#define DM 1024
#define DH 64

typedef __attribute__((ext_vector_type(8))) short bf16x8;
typedef __attribute__((ext_vector_type(4))) float f32x4;
typedef __attribute__((ext_vector_type(4))) short short4v;

__device__ inline short f2bf(float f) {
  union { float f; unsigned u; } x; x.f = f;
  unsigned r = x.u + 0x7FFFu + ((x.u >> 16) & 1u);
  return (short)(r >> 16);
}

// ---------------------------------------------------------------------------
// Kernel 0: W fp32 -> bf16, once. wbf[192][1024]: rows 0-63 Wq, 64-127 Wk,
// 128-191 Wv.
// ---------------------------------------------------------------------------
__global__ __launch_bounds__(256) void wconv_kernel(
    const float* __restrict__ Wq, const float* __restrict__ Wk,
    const float* __restrict__ Wv, short* __restrict__ wbf)
{
  const int tid = blockIdx.x * 256 + threadIdx.x;
  const int base = tid * 8;
  const int row = base >> 10;          // 0..191
  const int col = base & 1023;
  const float* src = (row < 64) ? Wq : (row < 128) ? Wk : Wv;
  src += (size_t)(row & 63) * DM + col;
  f32x4 f0 = ((const f32x4*)src)[0];
  f32x4 f1 = ((const f32x4*)src)[1];
  bf16x8 h = { f2bf(f0[0]), f2bf(f0[1]), f2bf(f0[2]), f2bf(f0[3]),
               f2bf(f1[0]), f2bf(f1[1]), f2bf(f1[2]), f2bf(f1[3]) };
  *(bf16x8*)(wbf + (size_t)row * DM + col) = h;
}

// ---------------------------------------------------------------------------
// Kernel 1: QKV projection, depth-2 pipelined. 256 blocks x 512 threads,
// 32-row x 192-col tile, BK=64, 16 iters. At iter it: issue loads for it+2,
// compute it from LDS, ds_write it+1's regs (issued a FULL iteration ago ->
// latency covered; compiler emits counted vmcnt, never 0). Static rA/rB
// ping-pong via full unroll (no runtime reg indexing).
// ---------------------------------------------------------------------------
__global__ __launch_bounds__(512) void proj_kernel(
    const float* __restrict__ X, const short* __restrict__ wbf,
    short* __restrict__ qout, short* __restrict__ kout,
    short* __restrict__ vtout)
{
  __shared__ short x_lds[2][32][80];
  __shared__ short w_lds[2][192][80];

  const int t = threadIdx.x;
  const int l = t & 63;
  const int w = t >> 6;                 // 0..7
  const int m0 = blockIdx.x * 32;

  f32x4 acc[3];
#pragma unroll
  for (int i = 0; i < 3; i++) acc[i] = (f32x4){0.f, 0.f, 0.f, 0.f};

  const int xr = t >> 4;                // 0..31
  const int xc = (t & 15) * 4;          // float cols 0..60
  const int wr = t >> 3;                // 0..63
  const int wc = (t & 7) * 8;           // bf16 cols 0..56

  const float* xsrc  = X   + (size_t)(m0 + xr) * DM + xc;
  const short* wsrc0 = wbf + (size_t)(wr)       * DM + wc;
  const short* wsrc1 = wbf + (size_t)(64 + wr)  * DM + wc;
  const short* wsrc2 = wbf + (size_t)(128 + wr) * DM + wc;

  // prologue: stage k-step 0 into buf0
  {
    f32x4 f = *(const f32x4*)xsrc;
    short4v h = { f2bf(f[0]), f2bf(f[1]), f2bf(f[2]), f2bf(f[3]) };
    *(short4v*)&x_lds[0][xr][xc] = h;
    *(bf16x8*)&w_lds[0][wr][wc]       = *(const bf16x8*)wsrc0;
    *(bf16x8*)&w_lds[0][64 + wr][wc]  = *(const bf16x8*)wsrc1;
    *(bf16x8*)&w_lds[0][128 + wr][wc] = *(const bf16x8*)wsrc2;
  }
  // issue k-step 1 loads into rA (in flight across the barrier)
  f32x4 xA = *(const f32x4*)(xsrc + 64);
  bf16x8 wA0 = *(const bf16x8*)(wsrc0 + 64);
  bf16x8 wA1 = *(const bf16x8*)(wsrc1 + 64);
  bf16x8 wA2 = *(const bf16x8*)(wsrc2 + 64);
  f32x4 xB;
  bf16x8 wB0, wB1, wB2;
  __syncthreads();

#pragma unroll
  for (int it = 0; it < 16; it++) {
    const int buf = it & 1;
    const int k2 = (it + 2) * 64;

    // issue loads for iter it+2 (static ping-pong: even->rB, odd->rA)
    if ((it & 1) == 0) {
      if (it + 2 < 16) {
        xB  = *(const f32x4*)(xsrc + k2);
        wB0 = *(const bf16x8*)(wsrc0 + k2);
        wB1 = *(const bf16x8*)(wsrc1 + k2);
        wB2 = *(const bf16x8*)(wsrc2 + k2);
      }
    } else {
      if (it + 2 < 16) {
        xA  = *(const f32x4*)(xsrc + k2);
        wA0 = *(const bf16x8*)(wsrc0 + k2);
        wA1 = *(const bf16x8*)(wsrc1 + k2);
        wA2 = *(const bf16x8*)(wsrc2 + k2);
      }
    }

    // compute from lds[buf]
    const short* xp = &x_lds[buf][(w & 1) * 16 + (l & 15)][(l >> 4) << 3];
    bf16x8 a0 = *(const bf16x8*)xp;
    bf16x8 a1 = *(const bf16x8*)(xp + 32);
#pragma unroll
    for (int nf = 0; nf < 3; nf++) {
      const int cf = (w >> 1) * 3 + nf;
      const short* wp = &w_lds[buf][cf * 16 + (l & 15)][(l >> 4) << 3];
      bf16x8 b0 = *(const bf16x8*)wp;
      bf16x8 b1 = *(const bf16x8*)(wp + 32);
      acc[nf] = __builtin_amdgcn_mfma_f32_16x16x32_bf16(a0, b0, acc[nf], 0, 0, 0);
      acc[nf] = __builtin_amdgcn_mfma_f32_16x16x32_bf16(a1, b1, acc[nf], 0, 0, 0);
    }

    // ds_write iter it+1's regs (issued one full iteration ago)
    if (it < 15) {
      if ((it & 1) == 0) {
        short4v h = { f2bf(xA[0]), f2bf(xA[1]), f2bf(xA[2]), f2bf(xA[3]) };
        *(short4v*)&x_lds[buf ^ 1][xr][xc] = h;
        *(bf16x8*)&w_lds[buf ^ 1][wr][wc]       = wA0;
        *(bf16x8*)&w_lds[buf ^ 1][64 + wr][wc]  = wA1;
        *(bf16x8*)&w_lds[buf ^ 1][128 + wr][wc] = wA2;
      } else {
        short4v h = { f2bf(xB[0]), f2bf(xB[1]), f2bf(xB[2]), f2bf(xB[3]) };
        *(short4v*)&x_lds[buf ^ 1][xr][xc] = h;
        *(bf16x8*)&w_lds[buf ^ 1][wr][wc]       = wB0;
        *(bf16x8*)&w_lds[buf ^ 1][64 + wr][wc]  = wB1;
        *(bf16x8*)&w_lds[buf ^ 1][128 + wr][wc] = wB2;
      }
    }
    __syncthreads();
  }

  // epilogue: C row=(lane>>4)*4+reg, col=cf*16+(lane&15)  [m89]
  const int rowb = m0 + (w & 1) * 16 + ((l >> 4) << 2);
#pragma unroll
  for (int nf = 0; nf < 3; nf++) {
    const int c = ((w >> 1) * 3 + nf) * 16 + (l & 15);
#pragma unroll
    for (int j = 0; j < 4; j++) {
      const int row = rowb + j;
      const float v = acc[nf][j];
      if (c < 64) {
        qout[row * DH + c] = f2bf(v * 0.03125f);  // fold 1/sqrt(1024)=1/32
      } else if (c < 128) {
        kout[row * DH + (c - 64)] = f2bf(v);
      } else {
        const int b = row >> 11, s = row & (SEQ - 1);
        vtout[b * (DH * SEQ) + (c - 128) * SEQ + s] = f2bf(v);
      }
    }
  }
}

// ---------------------------------------------------------------------------
// Kernel 2: split-KV causal flash (unchanged).
// ---------------------------------------------------------------------------
__global__ __launch_bounds__(256) void flash_kernel(
    const short* __restrict__ qin, const short* __restrict__ kin,
    const short* __restrict__ vtin, float* __restrict__ po,
    float* __restrict__ pm, float* __restrict__ pl,
    const int nck, const int cht)
{
  __shared__ short k_lds[2][64][72];
  __shared__ short vt_lds[2][64][72];
  __shared__ short p_lds[4][16][72];

  const int qt = blockIdx.x;
  const int ck = blockIdx.y;
  const int t0 = ck * cht;
  if (t0 > qt) return;
  const int b = blockIdx.z;

  const int t = threadIdx.x;
  const int l = t & 63;
  const int w = t >> 6;
  const int q0 = qt * 64;
  const int tend = min(t0 + cht, qt + 1);

  const short* qb = qin  + (size_t)b * SEQ * DH;
  const short* kb = kin  + (size_t)b * SEQ * DH;
  const short* vb = vtin + (size_t)b * DH * SEQ;

  const short* qr = qb + (size_t)(q0 + w * 16 + (l & 15)) * DH + ((l >> 4) << 3);
  const bf16x8 qf0 = *(const bf16x8*)qr;
  const bf16x8 qf1 = *(const bf16x8*)(qr + 32);

  f32x4 o[4];
#pragma unroll
  for (int i = 0; i < 4; i++) o[i] = (f32x4){0.f, 0.f, 0.f, 0.f};
  float m_run[4] = {-1e30f, -1e30f, -1e30f, -1e30f};
  float l_run[4] = {0.f, 0.f, 0.f, 0.f};

  const int sr = t >> 3;
  const int sc = (t & 7) * 8;

  {
    const int j0 = t0 * 64;
#pragma unroll
    for (int i = 0; i < 2; i++) {
      const int r = sr + i * 32;
      *(bf16x8*)&k_lds[0][r][sc]  = *(const bf16x8*)(kb + (size_t)(j0 + r) * DH + sc);
      *(bf16x8*)&vt_lds[0][r][sc] = *(const bf16x8*)(vb + (size_t)r * SEQ + j0 + sc);
    }
  }
  __syncthreads();

  for (int tt = t0; tt < tend; tt++) {
    const int bi = (tt - t0) & 1;
    const int j0 = tt * 64;
    const bool pf = (tt + 1 < tend);

    bf16x8 kpf0, kpf1, vpf0, vpf1;
    if (pf) {
      const int j1 = j0 + 64;
      kpf0 = *(const bf16x8*)(kb + (size_t)(j1 + sr) * DH + sc);
      kpf1 = *(const bf16x8*)(kb + (size_t)(j1 + sr + 32) * DH + sc);
      vpf0 = *(const bf16x8*)(vb + (size_t)sr * SEQ + j1 + sc);
      vpf1 = *(const bf16x8*)(vb + (size_t)(sr + 32) * SEQ + j1 + sc);
    }

    f32x4 s[4];
#pragma unroll
    for (int nf = 0; nf < 4; nf++) {
      const short* kr = &k_lds[bi][nf * 16 + (l & 15)][(l >> 4) << 3];
      bf16x8 b0 = *(const bf16x8*)kr;
      bf16x8 b1 = *(const bf16x8*)(kr + 32);
      f32x4 a = (f32x4){0.f, 0.f, 0.f, 0.f};
      a = __builtin_amdgcn_mfma_f32_16x16x32_bf16(qf0, b0, a, 0, 0, 0);
      a = __builtin_amdgcn_mfma_f32_16x16x32_bf16(qf1, b1, a, 0, 0, 0);
      s[nf] = a;
    }

    {
      const int growb = q0 + w * 16 + ((l >> 4) << 2);
#pragma unroll
      for (int nf = 0; nf < 4; nf++) {
        const int gcol = j0 + nf * 16 + (l & 15);
#pragma unroll
        for (int j = 0; j < 4; j++)
          if (gcol > growb + j) s[nf][j] = -1e30f;
      }
    }

    float alpha[4];
#pragma unroll
    for (int j = 0; j < 4; j++) {
      float tm = fmaxf(fmaxf(s[0][j], s[1][j]), fmaxf(s[2][j], s[3][j]));
      tm = fmaxf(tm, __shfl_xor(tm, 1));
      tm = fmaxf(tm, __shfl_xor(tm, 2));
      tm = fmaxf(tm, __shfl_xor(tm, 4));
      tm = fmaxf(tm, __shfl_xor(tm, 8));
      const float mn = fmaxf(m_run[j], tm);
      alpha[j] = exp2f((m_run[j] - mn) * 1.44269504f);
      m_run[j] = mn;
      float rs = 0.f;
#pragma unroll
      for (int nf = 0; nf < 4; nf++) {
        const float p = exp2f((s[nf][j] - mn) * 1.44269504f);
        s[nf][j] = p;
        rs += p;
      }
      rs += __shfl_xor(rs, 1);
      rs += __shfl_xor(rs, 2);
      rs += __shfl_xor(rs, 4);
      rs += __shfl_xor(rs, 8);
      l_run[j] = l_run[j] * alpha[j] + rs;
    }
#pragma unroll
    for (int df = 0; df < 4; df++)
#pragma unroll
      for (int j = 0; j < 4; j++) o[df][j] *= alpha[j];

#pragma unroll
    for (int nf = 0; nf < 4; nf++)
#pragma unroll
      for (int j = 0; j < 4; j++)
        p_lds[w][((l >> 4) << 2) + j][nf * 16 + (l & 15)] = f2bf(s[nf][j]);

    asm volatile("s_waitcnt lgkmcnt(0)" ::: "memory");
    __builtin_amdgcn_sched_barrier(0);

#pragma unroll
    for (int ks = 0; ks < 2; ks++) {
      const short* pr = &p_lds[w][l & 15][ks * 32 + ((l >> 4) << 3)];
      const bf16x8 pa = *(const bf16x8*)pr;
#pragma unroll
      for (int df = 0; df < 4; df++) {
        const short* vr = &vt_lds[bi][df * 16 + (l & 15)][ks * 32 + ((l >> 4) << 3)];
        const bf16x8 vf = *(const bf16x8*)vr;
        o[df] = __builtin_amdgcn_mfma_f32_16x16x32_bf16(pa, vf, o[df], 0, 0, 0);
      }
    }

    if (pf) {
      *(bf16x8*)&k_lds[bi ^ 1][sr][sc]       = kpf0;
      *(bf16x8*)&k_lds[bi ^ 1][sr + 32][sc]  = kpf1;
      *(bf16x8*)&vt_lds[bi ^ 1][sr][sc]      = vpf0;
      *(bf16x8*)&vt_lds[bi ^ 1][sr + 32][sc] = vpf1;
    }
    __syncthreads();
  }

  const int rowb = q0 + w * 16 + ((l >> 4) << 2);
#pragma unroll
  for (int j = 0; j < 4; j++) {
    const size_t rowg = (size_t)b * SEQ + rowb + j;
#pragma unroll
    for (int df = 0; df < 4; df++)
      po[(rowg * nck + ck) * DH + df * 16 + (l & 15)] = o[df][j];
    if ((l & 15) == 0) {
      pm[rowg * nck + ck] = m_run[j];
      pl[rowg * nck + ck] = l_run[j];
    }
  }
}

// ---------------------------------------------------------------------------
// Kernel 3: merge partials (unchanged).
// ---------------------------------------------------------------------------
__global__ __launch_bounds__(256) void merge_kernel(
    const float* __restrict__ po, const float* __restrict__ pm,
    const float* __restrict__ pl, float* __restrict__ out,
    const int nck, const int ckshift)
{
  const int gid = blockIdx.x * 256 + threadIdx.x;
  const int r = gid >> 6;
  const int d = gid & 63;
  const int s = r & (SEQ - 1);
  const int C = (s >> ckshift) + 1;

  float m = -1e30f;
  for (int c = 0; c < C; c++) m = fmaxf(m, pm[r * nck + c]);
  float den = 0.f, num = 0.f;
  for (int c = 0; c < C; c++) {
    const float wgt = exp2f((pm[r * nck + c] - m) * 1.44269504f);
    den += pl[r * nck + c] * wgt;
    num += po[(size_t)(r * nck + c) * DH + d] * wgt;
  }
  out[gid] = num / den;
}

extern "C" void kernel_launch(void* const* d_in, const int* in_sizes, int n_in,
                              void* d_out, int out_size, void* d_ws, size_t ws_size,
                              hipStream_t stream) {
  const float* X  = (const float*)d_in[0];
  const float* Wq = (const float*)d_in[1];
  const float* Wk = (const float*)d_in[2];
  const float* Wv = (const float*)d_in[3];

  const size_t nrow = (size_t)NB * SEQ;              // 8192
  short* qws  = (short*)d_ws;                        // [8192][64] bf16
  short* kws  = qws + nrow * DH;                     // [8192][64] bf16
  short* vtws = kws + nrow * DH;                     // [4][64][2048] bf16 (V^T)
  float* po   = (float*)(vtws + nrow * DH);          // [8192][nck][64] f32
  // wbf ALIASES the po region: wconv writes it, proj reads it, then flash
  // overwrites with po. Sequential on stream + rewritten every call -> safe.
  short* wbf  = (short*)po;                          // [192][1024] bf16
  const size_t qkv_bytes = 3 * nrow * DH * sizeof(short);

  int nck, cht, ckshift;
  {
    const size_t need4 = qkv_bytes + nrow * 4 * (DH + 2) * sizeof(float);
    if (ws_size >= need4) { nck = 4; cht = 8;  ckshift = 9;  }
    else                  { nck = 1; cht = 32; ckshift = 11; }
  }
  float* pm = po + nrow * nck * DH;
  float* pl = pm + nrow * nck;

  wconv_kernel<<<dim3(96), 256, 0, stream>>>(Wq, Wk, Wv, wbf);
  proj_kernel<<<dim3(NB * SEQ / 32), 512, 0, stream>>>(X, wbf, qws, kws, vtws);
  flash_kernel<<<dim3(SEQ / 64, nck, NB), 256, 0, stream>>>(qws, kws, vtws, po, pm, pl, nck, cht);
  merge_kernel<<<dim3(NB * SEQ * DH / 256), 256, 0, stream>>>(po, pm, pl, (float*)d_out, nck, ckshift);
}